// Round 7
// baseline (247.553 us; speedup 1.0000x reference)
//
#include <hip/hip_runtime.h>

#define B_ 32
#define T_ 2048
#define N_ 128
#define K_ 5
#define BN_ (B_ * N_)
#define PMAX_ 512
#define MINP_ 2

static constexpr double PI_D = 3.14159265358979323846264338327950288;
static constexpr double S2_D = 0.70710678118654752440084436210485;  // sqrt(1/2)

struct cd { double r, i; };

__device__ __forceinline__ void bf_w(cd& u, cd& v, double wr, double wi) {
    const double tr = v.r * wr - v.i * wi;
    const double ti = v.r * wi + v.i * wr;
    v.r = u.r - tr; v.i = u.i - ti;
    u.r += tr;      u.i += ti;
}
__device__ __forceinline__ void bf_1(cd& u, cd& v) {        // w = 1
    const double tr = v.r, ti = v.i;
    v.r = u.r - tr; v.i = u.i - ti;
    u.r += tr;      u.i += ti;
}
__device__ __forceinline__ void bf_mi(cd& u, cd& v) {       // w = -i
    const double tr = v.i, ti = -v.r;
    v.r = u.r - tr; v.i = u.i - ti;
    u.r += tr;      u.i += ti;
}
// LDS bank swizzle for the fp64 re/im arrays: every hot access pattern <=4-way.
__device__ __forceinline__ int sw(int i) { return i ^ ((i >> 5) & 31); }

// ---------------------------------------------------------------------------
// Kernel 0: twiddle table tw[m] = exp(-2*pi*i*m/2048), m=0..1023, into d_ws.
// ---------------------------------------------------------------------------
__global__ __launch_bounds__(256) void pt_twiddle(double2* __restrict__ tw) {
    const int m = blockIdx.x * 256 + threadIdx.x;
    if (m < 1024) {
        double s, c;
        sincos(-2.0 * PI_D * (double)m / 2048.0, &s, &c);
        tw[m] = make_double2(c, s);
    }
}

// ---------------------------------------------------------------------------
// Main kernel: per-PAIR-of-sequences. x columns in registers, fp64 radix-8
// FFT (z = a+i*b), mag^2 in registers, BARRIER-FREE per-wave top-5 +
// single-merge (2 barriers total in top-k), owner-write tile rows.
// LDS = re/im only (~33 KB) -> 4 blocks/CU.
// ---------------------------------------------------------------------------
__global__ __launch_bounds__(256, 4) void pt_fft_tiles(const float* __restrict__ x,
                                                       float* __restrict__ out,
                                                       const double2* __restrict__ tw) {
    __shared__ double re[2048];
    __shared__ double im[2048];
    __shared__ double wcv[2][4][K_];   // per-series, per-wave top-5 values
    __shared__ int    wck[2][4][K_];   // per-series, per-wave top-5 indices
    __shared__ int    sh_take[2][K_];

    // XCD-aware swizzle: blocks with equal (blockIdx & 7) (likely same XCD)
    // get consecutive q -> adjacent x columns -> L2 line reuse.
    const int i0  = blockIdx.x;
    const int q   = ((i0 & 7) << 8) | (i0 >> 3);
    const int bn0 = q * 2;
    const int b   = bn0 >> 7;          // / N_
    const int n   = bn0 & 127;         // even
    const int tid = threadIdx.x;

    // ---- Load x columns (n, n+1) into registers (8 float2, batched issue).
    const float* xp = x + (size_t)b * T_ * N_ + n;
    float2 v[8];
#pragma unroll
    for (int m = 0; m < 8; ++m)
        v[m] = *(const float2*)(xp + (size_t)(tid + 256 * m) * N_);

    // Bit-reversed complex pack into LDS.
#pragma unroll
    for (int m = 0; m < 8; ++m) {
        const int t = tid + 256 * m;
        const int p = sw((int)(__brev((unsigned)t) >> 21));   // pos = rev11(t)
        re[p] = (double)v[m].x;
        im[p] = (double)v[m].y;
    }
    __syncthreads();

    // ---- Round 1: radix-8 (stages 1-3), h=1, constant twiddles.
    {
        const int base = tid * 8;
        cd E[8];
#pragma unroll
        for (int j = 0; j < 8; ++j) { const int p = sw(base + j); E[j].r = re[p]; E[j].i = im[p]; }
        bf_1(E[0], E[1]); bf_1(E[2], E[3]); bf_1(E[4], E[5]); bf_1(E[6], E[7]);
        bf_1(E[0], E[2]); bf_mi(E[1], E[3]); bf_1(E[4], E[6]); bf_mi(E[5], E[7]);
        bf_1(E[0], E[4]); bf_w(E[1], E[5], S2_D, -S2_D);
        bf_mi(E[2], E[6]); bf_w(E[3], E[7], -S2_D, -S2_D);
#pragma unroll
        for (int j = 0; j < 8; ++j) { const int p = sw(base + j); re[p] = E[j].r; im[p] = E[j].i; }
    }
    __syncthreads();

    // ---- Rounds 2,3: radix-8 at stages s=4 (h=8) and s=7 (h=64).
#pragma unroll
    for (int r = 0; r < 2; ++r) {
        const int s    = 4 + 3 * r;
        const int h    = 1 << (s - 1);
        const int bq   = tid & (h - 1);
        const int g    = tid >> (s - 1);
        const int base = g * 8 * h + bq;
        const double2 w1  = tw[bq << (11 - s)];
        const double2 w2a = tw[bq << (10 - s)];
        const double2 w2b = tw[(bq + h) << (10 - s)];
        const double2 w30 = tw[bq << (9 - s)];
        const double2 w31 = tw[(bq + h) << (9 - s)];
        const double2 w32 = tw[(bq + 2 * h) << (9 - s)];
        const double2 w33 = tw[(bq + 3 * h) << (9 - s)];
        cd E[8];
#pragma unroll
        for (int j = 0; j < 8; ++j) { const int p = sw(base + j * h); E[j].r = re[p]; E[j].i = im[p]; }
        bf_w(E[0], E[1], w1.x, w1.y);   bf_w(E[2], E[3], w1.x, w1.y);
        bf_w(E[4], E[5], w1.x, w1.y);   bf_w(E[6], E[7], w1.x, w1.y);
        bf_w(E[0], E[2], w2a.x, w2a.y); bf_w(E[1], E[3], w2b.x, w2b.y);
        bf_w(E[4], E[6], w2a.x, w2a.y); bf_w(E[5], E[7], w2b.x, w2b.y);
        bf_w(E[0], E[4], w30.x, w30.y); bf_w(E[1], E[5], w31.x, w31.y);
        bf_w(E[2], E[6], w32.x, w32.y); bf_w(E[3], E[7], w33.x, w33.y);
#pragma unroll
        for (int j = 0; j < 8; ++j) { const int p = sw(base + j * h); re[p] = E[j].r; im[p] = E[j].i; }
        __syncthreads();
    }

    // ---- Round 4: radix-4 (stages 10-11), h=512, 2 butterflies/thread.
#pragma unroll
    for (int u = 0; u < 2; ++u) {
        const int bb = tid + 256 * u;
        const double2 wA = tw[bb << 1];
        const double2 wB = tw[bb];
        const double2 wC = tw[bb + 512];
        const int p0 = sw(bb), p1 = sw(bb + 512), p2 = sw(bb + 1024), p3 = sw(bb + 1536);
        cd E0 = {re[p0], im[p0]}, E1 = {re[p1], im[p1]};
        cd E2 = {re[p2], im[p2]}, E3 = {re[p3], im[p3]};
        bf_w(E0, E1, wA.x, wA.y); bf_w(E2, E3, wA.x, wA.y);
        bf_w(E0, E2, wB.x, wB.y); bf_w(E1, E3, wC.x, wC.y);
        re[p0] = E0.r; im[p0] = E0.i; re[p1] = E1.r; im[p1] = E1.i;
        re[p2] = E2.r; im[p2] = E2.i; re[p3] = E3.r; im[p3] = E3.i;
    }
    __syncthreads();

    // ---- Unpack both spectra; 4*mag^2 kept in REGISTERS (k = 1+tid+256m).
    double magsA[4], magsB[4];
#pragma unroll
    for (int m = 0; m < 4; ++m) {
        const int k  = 1 + tid + 256 * m;          // 1..1024
        const int nk = 2048 - k;
        const int pk = sw(k), pn = sw(nk);
        const double zr = re[pk], zi = im[pk];
        const double yr = re[pn], yi = im[pn];
        const double ar = zr + yr, ai = zi - yi;
        const double br = zi + yi, bi = yr - zr;
        magsA[m] = ar * ar + ai * ai;
        magsB[m] = br * br + bi * bi;
    }

    // ---- Per-wave top-5, barrier-free (intra-wave shuffles only).
    // Each wave owns k in {1+tid+256m}: iteratively extract its 5 best
    // (v desc, k asc), masking its own winner in registers each round.
    const int wid  = tid >> 6;
    const int lane = tid & 63;
#pragma unroll
    for (int it = 0; it < K_; ++it) {
        double bvA = -1.0; int biA = 1 << 30;
        double bvB = -1.0; int biB = 1 << 30;
#pragma unroll
        for (int m = 0; m < 4; ++m) {
            const int k = 1 + tid + 256 * m;
            if (magsA[m] > bvA || (magsA[m] == bvA && k < biA)) { bvA = magsA[m]; biA = k; }
            if (magsB[m] > bvB || (magsB[m] == bvB && k < biB)) { bvB = magsB[m]; biB = k; }
        }
#pragma unroll
        for (int off = 32; off > 0; off >>= 1) {
            double v2 = __shfl_down(bvA, off); int i2 = __shfl_down(biA, off);
            if (v2 > bvA || (v2 == bvA && i2 < biA)) { bvA = v2; biA = i2; }
            v2 = __shfl_down(bvB, off); i2 = __shfl_down(biB, off);
            if (v2 > bvB || (v2 == bvB && i2 < biB)) { bvB = v2; biB = i2; }
        }
        // Broadcast wave winners from lane 0; mask them in-register.
        const double wvA = __shfl(bvA, 0); const int wiA = __shfl(biA, 0);
        const double wvB = __shfl(bvB, 0); const int wiB = __shfl(biB, 0);
        if (lane == 0) {
            wcv[0][wid][it] = wvA; wck[0][wid][it] = wiA;
            wcv[1][wid][it] = wvB; wck[1][wid][it] = wiB;
        }
#pragma unroll
        for (int m = 0; m < 4; ++m) {
            const int k = 1 + tid + 256 * m;
            if (k == wiA) magsA[m] = -1.0;
            if (k == wiB) magsB[m] = -1.0;
        }
    }
    __syncthreads();

    // ---- Final merge: top-5 of the 20 per-wave candidates, per series.
    // Thread 0 -> A, thread 1 -> B. Total order (v desc, k asc) => identical
    // result & tie semantics to global iterative selection.
    if (tid < 2) {
        double cv[20]; int ck[20];
#pragma unroll
        for (int w = 0; w < 4; ++w)
#pragma unroll
            for (int j = 0; j < K_; ++j) {
                cv[w * K_ + j] = wcv[tid][w][j];
                ck[w * K_ + j] = wck[tid][w][j];
            }
        unsigned used = 0;
#pragma unroll
        for (int it = 0; it < K_; ++it) {
            double vb = -2.0; int ib = 1 << 30; int sel = 0;
#pragma unroll
            for (int c = 0; c < 20; ++c) {
                if (used & (1u << c)) continue;
                if (cv[c] > vb || (cv[c] == vb && ck[c] < ib)) { vb = cv[c]; ib = ck[c]; sel = c; }
            }
            used |= (1u << sel);
            int period = T_ / ib;
            if (period > PMAX_) period = PMAX_;
            if (period < MINP_) period = MINP_;
            const int cyc = T_ / period;
            sh_take[tid][it] = (period << 16) | (period * cyc); // pack period|take
        }
    }
    __syncthreads();

    // ---- periods / cycles (ints as float32).
    const size_t TILES = (size_t)BN_ * K_ * T_;
    if (tid < 2 * K_) {
        const int s2 = tid / K_, k2 = tid % K_;
        const int pk   = sh_take[s2][k2];
        const int per  = pk >> 16;
        const int take = pk & 0xFFFF;
        out[TILES + (size_t)(bn0 + s2) * K_ + k2]                      = (float)per;
        out[TILES + (size_t)BN_ * K_ + (size_t)(bn0 + s2) * K_ + k2]   = (float)(take / per);
    }

    // ---- Tile rows: owner-writes from registers. For output row (s2,k):
    //   p = (t >= start) ? t - start : t + take;  val = (t >= start) ? seq[t] : 0
    // Bijection onto [0,T); lane-consecutive t -> consecutive p (coalesced).
    float* rowA = out + (size_t)bn0 * (K_ * T_);
#pragma unroll
    for (int s2 = 0; s2 < 2; ++s2) {
#pragma unroll
        for (int k = 0; k < K_; ++k) {
            const int take  = sh_take[s2][k] & 0xFFFF;
            const int start = T_ - take;
            float* dst = rowA + (size_t)(s2 * K_ + k) * T_;
#pragma unroll
            for (int m = 0; m < 8; ++m) {
                const int t   = tid + 256 * m;
                const bool lo = (t < start);
                const int p   = lo ? (t + take) : (t - start);
                const float val = lo ? 0.0f : (s2 ? v[m].y : v[m].x);
                __builtin_nontemporal_store(val, dst + p);
            }
        }
    }
}

// ---------------------------------------------------------------------------
extern "C" void kernel_launch(void* const* d_in, const int* in_sizes, int n_in,
                              void* d_out, int out_size, void* d_ws, size_t ws_size,
                              hipStream_t stream) {
    const float* x = (const float*)d_in[0];
    float* out = (float*)d_out;
    double2* tw = (double2*)d_ws;   // 16 KB twiddle table

    pt_twiddle<<<dim3(4), dim3(256), 0, stream>>>(tw);
    pt_fft_tiles<<<dim3(BN_ / 2), dim3(256), 0, stream>>>(x, out, tw);
}

// Round 8
// 232.934 us; speedup vs baseline: 1.0628x; 1.0628x over previous
//
#include <hip/hip_runtime.h>

#define B_ 32
#define T_ 2048
#define N_ 128
#define K_ 5
#define BN_ (B_ * N_)
#define PMAX_ 512
#define MINP_ 2

static constexpr double PI_D = 3.14159265358979323846264338327950288;
static constexpr float  S2_F = 0.70710678118654752440f;  // sqrt(1/2)

struct cf { float r, i; };

__device__ __forceinline__ void bf_w(cf& u, cf& v, float wr, float wi) {
    const float tr = v.r * wr - v.i * wi;
    const float ti = v.r * wi + v.i * wr;
    v.r = u.r - tr; v.i = u.i - ti;
    u.r += tr;      u.i += ti;
}
__device__ __forceinline__ void bf_1(cf& u, cf& v) {        // w = 1
    const float tr = v.r, ti = v.i;
    v.r = u.r - tr; v.i = u.i - ti;
    u.r += tr;      u.i += ti;
}
__device__ __forceinline__ void bf_mi(cf& u, cf& v) {       // w = -i
    const float tr = v.i, ti = -v.r;
    v.r = u.r - tr; v.i = u.i - ti;
    u.r += tr;      u.i += ti;
}
// LDS bank swizzle: keeps every hot access pattern low-way on 32 banks.
__device__ __forceinline__ int sw(int i) { return i ^ ((i >> 5) & 31); }

// ---------------------------------------------------------------------------
// Kernel 0: twiddle table tw[m] = exp(-2*pi*i*m/2048) as float2, into d_ws.
// (computed in double, stored f32 — error ~ulp, same as reference's f32 FFT)
// ---------------------------------------------------------------------------
__global__ __launch_bounds__(256) void pt_twiddle(float2* __restrict__ tw) {
    const int m = blockIdx.x * 256 + threadIdx.x;
    if (m < 1024) {
        double s, c;
        sincos(-2.0 * PI_D * (double)m / 2048.0, &s, &c);
        tw[m] = make_float2((float)c, (float)s);
    }
}

// ---------------------------------------------------------------------------
// Main kernel (r5 topology, fp32): per-PAIR-of-sequences. x columns in
// registers, f32 radix-8 FFT (z = a+i*b), mag^2 back into LDS re/im,
// LDS-resident 128/128 top-5, owner-write tile rows.
// LDS = re/im f32 (~16.5 KB) -> 6 blocks/CU.
// ---------------------------------------------------------------------------
__global__ __launch_bounds__(256, 6) void pt_fft_tiles(const float* __restrict__ x,
                                                       float* __restrict__ out,
                                                       const float2* __restrict__ tw) {
    __shared__ float re[2048];
    __shared__ float im[2048];
    __shared__ float wredv[4];
    __shared__ int   wredi[4];
    __shared__ int   sh_take[2][K_];

    // XCD-aware swizzle: blocks with equal (blockIdx & 7) (likely same XCD)
    // get consecutive q -> adjacent x columns -> L2 line reuse.
    const int i0  = blockIdx.x;
    const int q   = ((i0 & 7) << 8) | (i0 >> 3);
    const int bn0 = q * 2;
    const int b   = bn0 >> 7;          // / N_
    const int n   = bn0 & 127;         // even
    const int tid = threadIdx.x;

    // ---- Load x columns (n, n+1) into registers (8 float2, batched issue).
    const float* xp = x + (size_t)b * T_ * N_ + n;
    float2 v[8];
#pragma unroll
    for (int m = 0; m < 8; ++m)
        v[m] = *(const float2*)(xp + (size_t)(tid + 256 * m) * N_);

    // Bit-reversed complex pack into LDS.
#pragma unroll
    for (int m = 0; m < 8; ++m) {
        const int t = tid + 256 * m;
        const int p = sw((int)(__brev((unsigned)t) >> 21));   // pos = rev11(t)
        re[p] = v[m].x;
        im[p] = v[m].y;
    }
    __syncthreads();

    // ---- Round 1: radix-8 (stages 1-3), h=1, constant twiddles.
    {
        const int base = tid * 8;
        cf E[8];
#pragma unroll
        for (int j = 0; j < 8; ++j) { const int p = sw(base + j); E[j].r = re[p]; E[j].i = im[p]; }
        bf_1(E[0], E[1]); bf_1(E[2], E[3]); bf_1(E[4], E[5]); bf_1(E[6], E[7]);
        bf_1(E[0], E[2]); bf_mi(E[1], E[3]); bf_1(E[4], E[6]); bf_mi(E[5], E[7]);
        bf_1(E[0], E[4]); bf_w(E[1], E[5], S2_F, -S2_F);
        bf_mi(E[2], E[6]); bf_w(E[3], E[7], -S2_F, -S2_F);
#pragma unroll
        for (int j = 0; j < 8; ++j) { const int p = sw(base + j); re[p] = E[j].r; im[p] = E[j].i; }
    }
    __syncthreads();

    // ---- Rounds 2,3: radix-8 at stages s=4 (h=8) and s=7 (h=64).
#pragma unroll
    for (int r = 0; r < 2; ++r) {
        const int s    = 4 + 3 * r;
        const int h    = 1 << (s - 1);
        const int bq   = tid & (h - 1);
        const int g    = tid >> (s - 1);
        const int base = g * 8 * h + bq;
        const float2 w1  = tw[bq << (11 - s)];
        const float2 w2a = tw[bq << (10 - s)];
        const float2 w2b = tw[(bq + h) << (10 - s)];
        const float2 w30 = tw[bq << (9 - s)];
        const float2 w31 = tw[(bq + h) << (9 - s)];
        const float2 w32 = tw[(bq + 2 * h) << (9 - s)];
        const float2 w33 = tw[(bq + 3 * h) << (9 - s)];
        cf E[8];
#pragma unroll
        for (int j = 0; j < 8; ++j) { const int p = sw(base + j * h); E[j].r = re[p]; E[j].i = im[p]; }
        bf_w(E[0], E[1], w1.x, w1.y);   bf_w(E[2], E[3], w1.x, w1.y);
        bf_w(E[4], E[5], w1.x, w1.y);   bf_w(E[6], E[7], w1.x, w1.y);
        bf_w(E[0], E[2], w2a.x, w2a.y); bf_w(E[1], E[3], w2b.x, w2b.y);
        bf_w(E[4], E[6], w2a.x, w2a.y); bf_w(E[5], E[7], w2b.x, w2b.y);
        bf_w(E[0], E[4], w30.x, w30.y); bf_w(E[1], E[5], w31.x, w31.y);
        bf_w(E[2], E[6], w32.x, w32.y); bf_w(E[3], E[7], w33.x, w33.y);
#pragma unroll
        for (int j = 0; j < 8; ++j) { const int p = sw(base + j * h); re[p] = E[j].r; im[p] = E[j].i; }
        __syncthreads();
    }

    // ---- Round 4: radix-4 (stages 10-11), h=512, 2 butterflies/thread.
#pragma unroll
    for (int u = 0; u < 2; ++u) {
        const int bb = tid + 256 * u;
        const float2 wA = tw[bb << 1];
        const float2 wB = tw[bb];
        const float2 wC = tw[bb + 512];
        const int p0 = sw(bb), p1 = sw(bb + 512), p2 = sw(bb + 1024), p3 = sw(bb + 1536);
        cf E0 = {re[p0], im[p0]}, E1 = {re[p1], im[p1]};
        cf E2 = {re[p2], im[p2]}, E3 = {re[p3], im[p3]};
        bf_w(E0, E1, wA.x, wA.y); bf_w(E2, E3, wA.x, wA.y);
        bf_w(E0, E2, wB.x, wB.y); bf_w(E1, E3, wC.x, wC.y);
        re[p0] = E0.r; im[p0] = E0.i; re[p1] = E1.r; im[p1] = E1.i;
        re[p2] = E2.r; im[p2] = E2.i; re[p3] = E3.r; im[p3] = E3.i;
    }
    __syncthreads();

    // ---- Unpack both spectra; 4*mag^2 (exact power-of-2 scale, rank-safe).
    float magsA[4], magsB[4];
#pragma unroll
    for (int m = 0; m < 4; ++m) {
        const int k  = 1 + tid + 256 * m;          // 1..1024
        const int nk = 2048 - k;
        const int pk = sw(k), pn = sw(nk);
        const float zr = re[pk], zi = im[pk];
        const float yr = re[pn], yi = im[pn];
        const float ar = zr + yr, ai = zi - yi;
        const float br = zi + yi, bi = yr - zr;
        magsA[m] = ar * ar + ai * ai;
        magsB[m] = br * br + bi * bi;
    }
    __syncthreads();
#pragma unroll
    for (int m = 0; m < 4; ++m) {
        const int pk = sw(1 + tid + 256 * m);
        re[pk] = magsA[m];
        im[pk] = magsB[m];
    }
    __syncthreads();

    // ---- Top-5: threads 0..127 -> A (re), 128..255 -> B (im); shuffle reduce.
    const int half = tid >> 7;
    const int lt   = tid & 127;
    const int wid  = tid >> 6;
    float* marr = half ? im : re;
    for (int it = 0; it < K_; ++it) {
        float bestv = -2.0f;
        int   besti = 1 << 30;
#pragma unroll
        for (int m = 0; m < 8; ++m) {
            const int k = 1 + lt + 128 * m;        // 1..1024
            const float vv = marr[sw(k)];
            if (vv > bestv || (vv == bestv && k < besti)) { bestv = vv; besti = k; }
        }
#pragma unroll
        for (int off = 32; off > 0; off >>= 1) {
            const float v2 = __shfl_down(bestv, off);
            const int   i2 = __shfl_down(besti, off);
            if (v2 > bestv || (v2 == bestv && i2 < besti)) { bestv = v2; besti = i2; }
        }
        if ((tid & 63) == 0) { wredv[wid] = bestv; wredi[wid] = besti; }
        __syncthreads();
        if (lt == 0) {
            float vb = wredv[2 * half]; int ib = wredi[2 * half];
            const float v1 = wredv[2 * half + 1]; const int i1 = wredi[2 * half + 1];
            if (v1 > vb || (v1 == vb && i1 < ib)) { vb = v1; ib = i1; }
            marr[sw(ib)] = -1.0f;                  // exclude for next iter
            int period = T_ / ib;
            if (period > PMAX_) period = PMAX_;
            if (period < MINP_) period = MINP_;
            const int cyc = T_ / period;
            sh_take[half][it] = (period << 16) | (period * cyc); // pack period|take
        }
        __syncthreads();
    }

    // ---- periods / cycles (ints as float32).
    const size_t TILES = (size_t)BN_ * K_ * T_;
    if (tid < 2 * K_) {
        const int s2 = tid / K_, k2 = tid % K_;
        const int pk   = sh_take[s2][k2];
        const int per  = pk >> 16;
        const int take = pk & 0xFFFF;
        out[TILES + (size_t)(bn0 + s2) * K_ + k2]                      = (float)per;
        out[TILES + (size_t)BN_ * K_ + (size_t)(bn0 + s2) * K_ + k2]   = (float)(take / per);
    }

    // ---- Tile rows: owner-writes from registers. For output row (s2,k):
    //   p = (t >= start) ? t - start : t + take;  val = (t >= start) ? seq[t] : 0
    // Bijection onto [0,T); lane-consecutive t -> consecutive p (coalesced).
    float* rowA = out + (size_t)bn0 * (K_ * T_);
#pragma unroll
    for (int s2 = 0; s2 < 2; ++s2) {
#pragma unroll
        for (int k = 0; k < K_; ++k) {
            const int take  = sh_take[s2][k] & 0xFFFF;
            const int start = T_ - take;
            float* dst = rowA + (size_t)(s2 * K_ + k) * T_;
#pragma unroll
            for (int m = 0; m < 8; ++m) {
                const int t   = tid + 256 * m;
                const bool lo = (t < start);
                const int p   = lo ? (t + take) : (t - start);
                const float val = lo ? 0.0f : (s2 ? v[m].y : v[m].x);
                __builtin_nontemporal_store(val, dst + p);
            }
        }
    }
}

// ---------------------------------------------------------------------------
extern "C" void kernel_launch(void* const* d_in, const int* in_sizes, int n_in,
                              void* d_out, int out_size, void* d_ws, size_t ws_size,
                              hipStream_t stream) {
    const float* x = (const float*)d_in[0];
    float* out = (float*)d_out;
    float2* tw = (float2*)d_ws;   // 8 KB twiddle table

    pt_twiddle<<<dim3(4), dim3(256), 0, stream>>>(tw);
    pt_fft_tiles<<<dim3(BN_ / 2), dim3(256), 0, stream>>>(x, out, tw);
}

// Round 9
// 224.590 us; speedup vs baseline: 1.1022x; 1.0372x over previous
//
#include <hip/hip_runtime.h>

#define B_ 32
#define T_ 2048
#define N_ 128
#define K_ 5
#define BN_ (B_ * N_)
#define PMAX_ 512
#define MINP_ 2

static constexpr double PI_D = 3.14159265358979323846264338327950288;
static constexpr float  S2_F = 0.70710678118654752440f;  // sqrt(1/2)

struct cf { float r, i; };

__device__ __forceinline__ void bf_w(cf& u, cf& v, float wr, float wi) {
    const float tr = v.r * wr - v.i * wi;
    const float ti = v.r * wi + v.i * wr;
    v.r = u.r - tr; v.i = u.i - ti;
    u.r += tr;      u.i += ti;
}
__device__ __forceinline__ void bf_1(cf& u, cf& v) {        // w = 1
    const float tr = v.r, ti = v.i;
    v.r = u.r - tr; v.i = u.i - ti;
    u.r += tr;      u.i += ti;
}
__device__ __forceinline__ void bf_mi(cf& u, cf& v) {       // w = -i
    const float tr = v.i, ti = -v.r;
    v.r = u.r - tr; v.i = u.i - ti;
    u.r += tr;      u.i += ti;
}
// LDS bank swizzle: keeps every hot access pattern low-way on 32 banks.
__device__ __forceinline__ int sw(int i) { return i ^ ((i >> 5) & 31); }

// ---------------------------------------------------------------------------
// Kernel 0: twiddle table tw[m] = exp(-2*pi*i*m/2048) as float2, into d_ws.
// ---------------------------------------------------------------------------
__global__ __launch_bounds__(256) void pt_twiddle(float2* __restrict__ tw) {
    const int m = blockIdx.x * 256 + threadIdx.x;
    if (m < 1024) {
        double s, c;
        sincos(-2.0 * PI_D * (double)m / 2048.0, &s, &c);
        tw[m] = make_float2((float)c, (float)s);
    }
}

// ---------------------------------------------------------------------------
// Main kernel: fp32 radix-8 FFT (z = a+i*b) per sequence pair, LDS-resident
// top-5, tile rows emitted as ALIGNED float4 REGULAR stores from LDS seq
// (shifted-window reads) — same store shape as the 6.5 TB/s fill kernel.
// LDS ~33 KB -> 4 blocks/CU.
// ---------------------------------------------------------------------------
__global__ __launch_bounds__(256, 4) void pt_fft_tiles(const float* __restrict__ x,
                                                       float* __restrict__ out,
                                                       const float2* __restrict__ tw) {
    __shared__ float re[2048];
    __shared__ float im[2048];
    __shared__ __align__(16) float seqA[2052];   // +4 slack for shifted f4 reads
    __shared__ __align__(16) float seqB[2052];
    __shared__ float wredv[4];
    __shared__ int   wredi[4];
    __shared__ int   sh_take[2][K_];

    // XCD-aware swizzle: blocks with equal (blockIdx & 7) (likely same XCD)
    // get consecutive q -> adjacent x columns -> L2 line reuse.
    const int i0  = blockIdx.x;
    const int q   = ((i0 & 7) << 8) | (i0 >> 3);
    const int bn0 = q * 2;
    const int b   = bn0 >> 7;          // / N_
    const int n   = bn0 & 127;         // even
    const int tid = threadIdx.x;

    // ---- Load x columns (n, n+1): seq LDS arrays + bit-reversed pack.
    const float* xp = x + (size_t)b * T_ * N_ + n;
    float2 v[8];
#pragma unroll
    for (int m = 0; m < 8; ++m)
        v[m] = *(const float2*)(xp + (size_t)(tid + 256 * m) * N_);
#pragma unroll
    for (int m = 0; m < 8; ++m) {
        const int t = tid + 256 * m;
        seqA[t] = v[m].x;
        seqB[t] = v[m].y;
        const int p = sw((int)(__brev((unsigned)t) >> 21));   // pos = rev11(t)
        re[p] = v[m].x;
        im[p] = v[m].y;
    }
    __syncthreads();

    // ---- Round 1: radix-8 (stages 1-3), h=1, constant twiddles.
    {
        const int base = tid * 8;
        cf E[8];
#pragma unroll
        for (int j = 0; j < 8; ++j) { const int p = sw(base + j); E[j].r = re[p]; E[j].i = im[p]; }
        bf_1(E[0], E[1]); bf_1(E[2], E[3]); bf_1(E[4], E[5]); bf_1(E[6], E[7]);
        bf_1(E[0], E[2]); bf_mi(E[1], E[3]); bf_1(E[4], E[6]); bf_mi(E[5], E[7]);
        bf_1(E[0], E[4]); bf_w(E[1], E[5], S2_F, -S2_F);
        bf_mi(E[2], E[6]); bf_w(E[3], E[7], -S2_F, -S2_F);
#pragma unroll
        for (int j = 0; j < 8; ++j) { const int p = sw(base + j); re[p] = E[j].r; im[p] = E[j].i; }
    }
    __syncthreads();

    // ---- Rounds 2,3: radix-8 at stages s=4 (h=8) and s=7 (h=64).
#pragma unroll
    for (int r = 0; r < 2; ++r) {
        const int s    = 4 + 3 * r;
        const int h    = 1 << (s - 1);
        const int bq   = tid & (h - 1);
        const int g    = tid >> (s - 1);
        const int base = g * 8 * h + bq;
        const float2 w1  = tw[bq << (11 - s)];
        const float2 w2a = tw[bq << (10 - s)];
        const float2 w2b = tw[(bq + h) << (10 - s)];
        const float2 w30 = tw[bq << (9 - s)];
        const float2 w31 = tw[(bq + h) << (9 - s)];
        const float2 w32 = tw[(bq + 2 * h) << (9 - s)];
        const float2 w33 = tw[(bq + 3 * h) << (9 - s)];
        cf E[8];
#pragma unroll
        for (int j = 0; j < 8; ++j) { const int p = sw(base + j * h); E[j].r = re[p]; E[j].i = im[p]; }
        bf_w(E[0], E[1], w1.x, w1.y);   bf_w(E[2], E[3], w1.x, w1.y);
        bf_w(E[4], E[5], w1.x, w1.y);   bf_w(E[6], E[7], w1.x, w1.y);
        bf_w(E[0], E[2], w2a.x, w2a.y); bf_w(E[1], E[3], w2b.x, w2b.y);
        bf_w(E[4], E[6], w2a.x, w2a.y); bf_w(E[5], E[7], w2b.x, w2b.y);
        bf_w(E[0], E[4], w30.x, w30.y); bf_w(E[1], E[5], w31.x, w31.y);
        bf_w(E[2], E[6], w32.x, w32.y); bf_w(E[3], E[7], w33.x, w33.y);
#pragma unroll
        for (int j = 0; j < 8; ++j) { const int p = sw(base + j * h); re[p] = E[j].r; im[p] = E[j].i; }
        __syncthreads();
    }

    // ---- Round 4: radix-4 (stages 10-11), h=512, 2 butterflies/thread.
#pragma unroll
    for (int u = 0; u < 2; ++u) {
        const int bb = tid + 256 * u;
        const float2 wA = tw[bb << 1];
        const float2 wB = tw[bb];
        const float2 wC = tw[bb + 512];
        const int p0 = sw(bb), p1 = sw(bb + 512), p2 = sw(bb + 1024), p3 = sw(bb + 1536);
        cf E0 = {re[p0], im[p0]}, E1 = {re[p1], im[p1]};
        cf E2 = {re[p2], im[p2]}, E3 = {re[p3], im[p3]};
        bf_w(E0, E1, wA.x, wA.y); bf_w(E2, E3, wA.x, wA.y);
        bf_w(E0, E2, wB.x, wB.y); bf_w(E1, E3, wC.x, wC.y);
        re[p0] = E0.r; im[p0] = E0.i; re[p1] = E1.r; im[p1] = E1.i;
        re[p2] = E2.r; im[p2] = E2.i; re[p3] = E3.r; im[p3] = E3.i;
    }
    __syncthreads();

    // ---- Unpack both spectra; 4*mag^2 (exact power-of-2 scale, rank-safe).
    float magsA[4], magsB[4];
#pragma unroll
    for (int m = 0; m < 4; ++m) {
        const int k  = 1 + tid + 256 * m;          // 1..1024
        const int nk = 2048 - k;
        const int pk = sw(k), pn = sw(nk);
        const float zr = re[pk], zi = im[pk];
        const float yr = re[pn], yi = im[pn];
        const float ar = zr + yr, ai = zi - yi;
        const float br = zi + yi, bi = yr - zr;
        magsA[m] = ar * ar + ai * ai;
        magsB[m] = br * br + bi * bi;
    }
    __syncthreads();
#pragma unroll
    for (int m = 0; m < 4; ++m) {
        const int pk = sw(1 + tid + 256 * m);
        re[pk] = magsA[m];
        im[pk] = magsB[m];
    }
    __syncthreads();

    // ---- Top-5: threads 0..127 -> A (re), 128..255 -> B (im); shuffle reduce.
    const int half = tid >> 7;
    const int lt   = tid & 127;
    const int wid  = tid >> 6;
    float* marr = half ? im : re;
    for (int it = 0; it < K_; ++it) {
        float bestv = -2.0f;
        int   besti = 1 << 30;
#pragma unroll
        for (int m = 0; m < 8; ++m) {
            const int k = 1 + lt + 128 * m;        // 1..1024
            const float vv = marr[sw(k)];
            if (vv > bestv || (vv == bestv && k < besti)) { bestv = vv; besti = k; }
        }
#pragma unroll
        for (int off = 32; off > 0; off >>= 1) {
            const float v2 = __shfl_down(bestv, off);
            const int   i2 = __shfl_down(besti, off);
            if (v2 > bestv || (v2 == bestv && i2 < besti)) { bestv = v2; besti = i2; }
        }
        if ((tid & 63) == 0) { wredv[wid] = bestv; wredi[wid] = besti; }
        __syncthreads();
        if (lt == 0) {
            float vb = wredv[2 * half]; int ib = wredi[2 * half];
            const float v1 = wredv[2 * half + 1]; const int i1 = wredi[2 * half + 1];
            if (v1 > vb || (v1 == vb && i1 < ib)) { vb = v1; ib = i1; }
            marr[sw(ib)] = -1.0f;                  // exclude for next iter
            int period = T_ / ib;
            if (period > PMAX_) period = PMAX_;
            if (period < MINP_) period = MINP_;
            const int cyc = T_ / period;
            sh_take[half][it] = (period << 16) | (period * cyc); // pack period|take
        }
        __syncthreads();
    }

    // ---- periods / cycles (ints as float32).
    const size_t TILES = (size_t)BN_ * K_ * T_;
    if (tid < 2 * K_) {
        const int s2 = tid / K_, k2 = tid % K_;
        const int pk   = sh_take[s2][k2];
        const int per  = pk >> 16;
        const int take = pk & 0xFFFF;
        out[TILES + (size_t)(bn0 + s2) * K_ + k2]                      = (float)per;
        out[TILES + (size_t)BN_ * K_ + (size_t)(bn0 + s2) * K_ + k2]   = (float)(take / per);
    }

    // ---- Tile rows: aligned f4 LDS reads + register shift, REGULAR aligned
    // float4 stores (same shape as the 6.5 TB/s fill kernel).
    float* rowA = out + (size_t)bn0 * (K_ * T_);
#pragma unroll
    for (int m = 0; m < 20; ++m) {
        const int e  = tid + 256 * m;
        const int s2 = (e >= K_ * (T_ / 4)) ? 1 : 0;
        const int w  = e - s2 * (K_ * (T_ / 4));
        const int k  = w >> 9;                     // / 512
        const int p4 = (w & 511) << 2;
        const int take  = sh_take[s2][k] & 0xFFFF;
        const int start = T_ - take;
        const float4* sq4 = (const float4*)(s2 ? seqB : seqA);
        const int idx = start + p4;
        int a0 = idx >> 2;
        if (a0 > 511) a0 = 511;                    // clamp (masked anyway)
        const int sh = idx & 3;
        const float4 lo = sq4[a0];
        const float4 hi = sq4[a0 + 1];
        float r0, r1, r2, r3;
        if (sh == 0)      { r0 = lo.x; r1 = lo.y; r2 = lo.z; r3 = lo.w; }
        else if (sh == 1) { r0 = lo.y; r1 = lo.z; r2 = lo.w; r3 = hi.x; }
        else if (sh == 2) { r0 = lo.z; r1 = lo.w; r2 = hi.x; r3 = hi.y; }
        else              { r0 = lo.w; r1 = hi.x; r2 = hi.y; r3 = hi.z; }
        float4 vv;
        vv.x = (p4 + 0 < take) ? r0 : 0.0f;
        vv.y = (p4 + 1 < take) ? r1 : 0.0f;
        vv.z = (p4 + 2 < take) ? r2 : 0.0f;
        vv.w = (p4 + 3 < take) ? r3 : 0.0f;
        *(float4*)(rowA + (size_t)(s2 * K_ + k) * T_ + p4) = vv;
    }
}

// ---------------------------------------------------------------------------
extern "C" void kernel_launch(void* const* d_in, const int* in_sizes, int n_in,
                              void* d_out, int out_size, void* d_ws, size_t ws_size,
                              hipStream_t stream) {
    const float* x = (const float*)d_in[0];
    float* out = (float*)d_out;
    float2* tw = (float2*)d_ws;   // 8 KB twiddle table

    pt_twiddle<<<dim3(4), dim3(256), 0, stream>>>(tw);
    pt_fft_tiles<<<dim3(BN_ / 2), dim3(256), 0, stream>>>(x, out, tw);
}